// Round 1
// baseline (343.458 us; speedup 1.0000x reference)
//
#include <hip/hip_runtime.h>
#include <math.h>

#define NN 512
#define FF 32
#define RR 8
#define HH 128
#define EPSV 0.1f
#define INV_EPS 10.0f
#define CHUNK 64
#define NCHUNK (NN / CHUNK)

__device__ __forceinline__ float sp(float x) {
    // softplus, stable: max(x,0) + log1p(exp(-|x|))
    return fmaxf(x, 0.f) + __logf(1.f + __expf(-fabsf(x)));
}

// ---- K1: XWx = X@Wx [512,128], YWy = Y@Wy [512,128] ----
__global__ __launch_bounds__(256) void precompute_kernel(
    const float* __restrict__ X, const float* __restrict__ Y,
    const float* __restrict__ Wx, const float* __restrict__ Wy,
    float* __restrict__ XWx, float* __restrict__ YWy) {
    int gid = blockIdx.x * 256 + threadIdx.x;
    if (gid < NN * HH) {
        int i = gid >> 7, h = gid & 127;
        float s = 0.f;
#pragma unroll
        for (int f = 0; f < FF; ++f) s += X[i * FF + f] * Wx[f * HH + h];
        XWx[gid] = s;
    } else {
        int g = gid - NN * HH;
        int i = g >> 7, h = g & 127;
        float s = 0.f;
#pragma unroll
        for (int r = 0; r < RR; ++r) s += Y[i * RR + r] * Wy[r * HH + h];
        YWy[g] = s;
    }
}

// one fp32 layer: dst = softplus(src @ W + bias), src/dst are [64][128] LDS tiles
__device__ __forceinline__ void layer(const float* __restrict__ src, float* __restrict__ dst,
                                      const float* __restrict__ W, const float* bias8,
                                      int row0, int col0) {
    float acc[4][8];
#pragma unroll
    for (int rr = 0; rr < 4; ++rr)
#pragma unroll
        for (int cc = 0; cc < 8; ++cc) acc[rr][cc] = bias8[cc];

#pragma unroll 2
    for (int k = 0; k < HH; k += 4) {
        float4 a0 = *(const float4*)&src[(row0 + 0) * HH + k];
        float4 a1 = *(const float4*)&src[(row0 + 1) * HH + k];
        float4 a2 = *(const float4*)&src[(row0 + 2) * HH + k];
        float4 a3 = *(const float4*)&src[(row0 + 3) * HH + k];
#pragma unroll
        for (int kk = 0; kk < 4; ++kk) {
            float4 w0 = *(const float4*)&W[(k + kk) * HH + col0];
            float4 w1 = *(const float4*)&W[(k + kk) * HH + col0 + 4];
            float a_0 = kk == 0 ? a0.x : kk == 1 ? a0.y : kk == 2 ? a0.z : a0.w;
            float a_1 = kk == 0 ? a1.x : kk == 1 ? a1.y : kk == 2 ? a1.z : a1.w;
            float a_2 = kk == 0 ? a2.x : kk == 1 ? a2.y : kk == 2 ? a2.z : a2.w;
            float a_3 = kk == 0 ? a3.x : kk == 1 ? a3.y : kk == 2 ? a3.z : a3.w;
            const float wv[8] = {w0.x, w0.y, w0.z, w0.w, w1.x, w1.y, w1.z, w1.w};
#pragma unroll
            for (int cc = 0; cc < 8; ++cc) {
                acc[0][cc] += a_0 * wv[cc];
                acc[1][cc] += a_1 * wv[cc];
                acc[2][cc] += a_2 * wv[cc];
                acc[3][cc] += a_3 * wv[cc];
            }
        }
    }
#pragma unroll
    for (int rr = 0; rr < 4; ++rr) {
        float4 o0 = make_float4(sp(acc[rr][0]), sp(acc[rr][1]), sp(acc[rr][2]), sp(acc[rr][3]));
        float4 o1 = make_float4(sp(acc[rr][4]), sp(acc[rr][5]), sp(acc[rr][6]), sp(acc[rr][7]));
        *(float4*)&dst[(row0 + rr) * HH + col0] = o0;
        *(float4*)&dst[(row0 + rr) * HH + col0 + 4] = o1;
    }
}

// ---- K2: per row i, loop 8 chunks of 64 j's; batched MLP + online logsumexp ----
__global__ __launch_bounds__(256, 2) void pair_kernel(
    const float* __restrict__ XWx, const float* __restrict__ YWy,
    const float* __restrict__ U, const float* __restrict__ Y,
    const float* __restrict__ b0, const float* __restrict__ W1, const float* __restrict__ b1,
    const float* __restrict__ W2, const float* __restrict__ b2,
    const float* __restrict__ Wout, const float* __restrict__ bout,
    float* __restrict__ accum) {
    __shared__ float bufA[CHUNK * HH];  // H0 / H2
    __shared__ float bufB[CHUNK * HH];  // H1; epilogue: [0..127]=Wout copy, [128..191]=slack

    const int i = blockIdx.x;
    const int t = threadIdx.x;
    const int h_t = t & 127;
    const float axh = XWx[i * HH + h_t] + b0[h_t];

    const int tr = t >> 4;       // 0..15
    const int tc = t & 15;       // 0..15
    const int row0 = tr * 4;
    const int col0 = tc * 8;

    float b1r[8], b2r[8];
#pragma unroll
    for (int cc = 0; cc < 8; ++cc) {
        b1r[cc] = b1[col0 + cc];
        b2r[cc] = b2[col0 + cc];
    }
    const float boutv = bout[0];
    const int p_ep = t >> 2, q_ep = t & 3;

    float m_l = -INFINITY, s_l = 0.f;  // per-lane online LSE state (wave 0 lanes)

    for (int c = 0; c < NCHUNK; ++c) {
        const int j0 = c * CHUNK;
        // ---- stage H0 = softplus(XWx[i] + YWy[j] + b0) ----
#pragma unroll 4
        for (int s = 0; s < 32; ++s) {
            int p = (t >> 7) + 2 * s;
            float v = axh + YWy[(j0 + p) * HH + h_t];
            bufA[p * HH + h_t] = sp(v);
        }
        __syncthreads();
        // ---- layer 1 ----
        layer(bufA, bufB, W1, b1r, row0, col0);
        __syncthreads();
        // ---- layer 2 ----
        layer(bufB, bufA, W2, b2r, row0, col0);
        __syncthreads();
        // ---- epilogue: psi = h2 . Wout + bout ; slack = U[i].Y[j] - psi ----
        if (t < HH) bufB[t] = Wout[t];  // bufB free now
        __syncthreads();
        {
            float acc = 0.f;
            int base = p_ep * HH + q_ep * 32;
#pragma unroll
            for (int kk = 0; kk < 32; ++kk) {
                int kidx = (kk + t) & 31;  // bank-rotate: 2-way (free)
                acc += bufA[base + kidx] * bufB[q_ep * 32 + kidx];
            }
            acc += __shfl_xor(acc, 1);
            acc += __shfl_xor(acc, 2);
            if (q_ep == 0) {
                float psi = acc + boutv;
                int j = j0 + p_ep;
                float cost = 0.f;
#pragma unroll
                for (int r = 0; r < RR; ++r) cost += U[i * RR + r] * Y[j * RR + r];
                bufB[128 + p_ep] = cost - psi;
                if (j == i) atomicAdd(&accum[0], psi);  // diagonal = psi row term
            }
        }
        __syncthreads();
        // ---- online LSE update (wave 0, one lane per j in chunk) ----
        if (t < 64) {
            float sv = bufB[128 + t];
            float mn = fmaxf(m_l, sv);
            s_l = s_l * __expf((m_l - mn) * INV_EPS) + __expf((sv - mn) * INV_EPS);
            m_l = mn;
        }
        __syncthreads();
    }
    // ---- combine 64 lanes' (m,s), emit phi_i ----
    if (t < 64) {
        float M = m_l;
#pragma unroll
        for (int o = 1; o < 64; o <<= 1) M = fmaxf(M, __shfl_xor(M, o));
        float S = s_l * __expf((m_l - M) * INV_EPS);
#pragma unroll
        for (int o = 1; o < 64; o <<= 1) S += __shfl_xor(S, o);
        if (t == 0) {
            float phi = EPSV * (logf(S) - logf((float)NN)) + M;
            atomicAdd(&accum[1], phi);
        }
    }
}

__global__ void finalize_kernel(const float* __restrict__ accum, float* __restrict__ out) {
    out[0] = (accum[0] + accum[1]) / (float)NN;
}

extern "C" void kernel_launch(void* const* d_in, const int* in_sizes, int n_in,
                              void* d_out, int out_size, void* d_ws, size_t ws_size,
                              hipStream_t stream) {
    (void)in_sizes; (void)n_in; (void)out_size; (void)ws_size;
    const float* X    = (const float*)d_in[0];
    const float* U    = (const float*)d_in[1];
    const float* Y    = (const float*)d_in[2];
    const float* Wx   = (const float*)d_in[3];
    const float* Wy   = (const float*)d_in[4];
    const float* b0   = (const float*)d_in[5];
    const float* W1   = (const float*)d_in[6];
    const float* b1   = (const float*)d_in[7];
    const float* W2   = (const float*)d_in[8];
    const float* b2   = (const float*)d_in[9];
    const float* Wout = (const float*)d_in[10];
    const float* bout = (const float*)d_in[11];
    float* out = (float*)d_out;

    float* ws   = (float*)d_ws;
    float* XWx  = ws;                 // 512*128
    float* YWy  = ws + NN * HH;       // 512*128
    float* accum = ws + 2 * NN * HH;  // [0]=psi_sum, [1]=phi_sum

    hipMemsetAsync(accum, 0, 2 * sizeof(float), stream);
    precompute_kernel<<<(2 * NN * HH) / 256, 256, 0, stream>>>(X, Y, Wx, Wy, XWx, YWy);
    pair_kernel<<<NN, 256, 0, stream>>>(XWx, YWy, U, Y, b0, W1, b1, W2, b2, Wout, bout, accum);
    finalize_kernel<<<1, 1, 0, stream>>>(accum, out);
}

// Round 2
// 91.261 us; speedup vs baseline: 3.7635x; 3.7635x over previous
//
#include <hip/hip_runtime.h>
#include <math.h>

#define NN 512
#define HH 128
#define FF 32
#define RR 8
#define EPSV 0.1f
#define INV_EPS 10.0f

typedef unsigned short ushort_t;
typedef __attribute__((ext_vector_type(8))) short bf16x8;
typedef __attribute__((ext_vector_type(4))) float f32x4;

__device__ __forceinline__ float sp(float x) {
    // softplus, stable: max(x,0) + log(1+exp(-|x|))
    return fmaxf(x, 0.f) + __logf(1.f + __expf(-fabsf(x)));
}
__device__ __forceinline__ ushort_t f2b(float f) {  // fp32 -> bf16 RNE
    unsigned u = __float_as_uint(f);
    return (ushort_t)((u + 0x7fffu + ((u >> 16) & 1u)) >> 16);
}
__device__ __forceinline__ float b2f(ushort_t h) {
    return __uint_as_float(((unsigned)h) << 16);
}

// ---- K0: W1,W2 -> bf16 transposed [n][k] ----
__global__ __launch_bounds__(256) void prep_w_kernel(
    const float* __restrict__ W1, const float* __restrict__ W2,
    ushort_t* __restrict__ Wt1b, ushort_t* __restrict__ Wt2b) {
    int gid = blockIdx.x * 256 + threadIdx.x;       // 0..32767
    int sel = gid >> 14;
    int idx = gid & 16383;                          // = n*128 + k
    int n = idx >> 7, k = idx & 127;
    const float* src = sel ? W2 : W1;
    ushort_t* dst = sel ? Wt2b : Wt1b;
    dst[idx] = f2b(src[k * HH + n]);
}

// ---- K1: XWxb = bf16(X@Wx + b0), YWyb = bf16(Y@Wy) ----
__global__ __launch_bounds__(256) void prep_xy_kernel(
    const float* __restrict__ X, const float* __restrict__ Y,
    const float* __restrict__ Wx, const float* __restrict__ Wy,
    const float* __restrict__ b0,
    ushort_t* __restrict__ XWxb, ushort_t* __restrict__ YWyb) {
    int gid = blockIdx.x * 256 + threadIdx.x;
    if (gid < NN * HH) {
        int i = gid >> 7, h = gid & 127;
        float s = b0[h];
#pragma unroll
        for (int f = 0; f < FF; ++f) s += X[i * FF + f] * Wx[f * HH + h];
        XWxb[gid] = f2b(s);
    } else {
        int g = gid - NN * HH;
        int i = g >> 7, h = g & 127;
        float s = 0.f;
#pragma unroll
        for (int r = 0; r < RR; ++r) s += Y[i * RR + r] * Wy[r * HH + h];
        YWyb[g] = f2b(s);
    }
}

// one MFMA layer: Hout = softplus(Hin @ W + bias); Hin/Hout swizzled bf16 [64][128] LDS,
// WtG = bf16 W^T [n][k] in global. Wave wv owns cols [wv*32, wv*32+32), all 64 rows.
__device__ __forceinline__ void layer_mfma(
    const ushort_t* __restrict__ Hin, const ushort_t* __restrict__ WtG,
    ushort_t* __restrict__ Hout, const float* bias, int r16, int g4, int n0w) {
    f32x4 acc[4][2];
#pragma unroll
    for (int mt = 0; mt < 4; ++mt)
#pragma unroll
        for (int nt = 0; nt < 2; ++nt) {
            acc[mt][nt][0] = bias[nt]; acc[mt][nt][1] = bias[nt];
            acc[mt][nt][2] = bias[nt]; acc[mt][nt][3] = bias[nt];
        }
    // preload all B fragments (global, L1/L2-hot)
    bf16x8 bfr[4][2];
#pragma unroll
    for (int ks = 0; ks < 4; ++ks)
#pragma unroll
        for (int nt = 0; nt < 2; ++nt)
            bfr[ks][nt] = *(const bf16x8*)&WtG[(n0w + nt * 16 + r16) * HH + ks * 32 + g4 * 8];
#pragma unroll
    for (int ks = 0; ks < 4; ++ks) {
        const int kb = ks * 32 + g4 * 8;
#pragma unroll
        for (int mt = 0; mt < 4; ++mt) {
            const int row = mt * 16 + r16;
            bf16x8 afr = *(const bf16x8*)&Hin[row * HH + (kb ^ ((r16 & 7) << 3))];
#pragma unroll
            for (int nt = 0; nt < 2; ++nt)
                acc[mt][nt] = __builtin_amdgcn_mfma_f32_16x16x32_bf16(afr, bfr[ks][nt], acc[mt][nt], 0, 0, 0);
        }
    }
    // softplus + bf16 + swizzled store; C/D layout: row=(lane>>4)*4+reg, col=lane&15
#pragma unroll
    for (int mt = 0; mt < 4; ++mt)
#pragma unroll
        for (int nt = 0; nt < 2; ++nt)
#pragma unroll
            for (int r = 0; r < 4; ++r) {
                const int row = mt * 16 + g4 * 4 + r;
                const int col = n0w + nt * 16 + r16;
                Hout[row * HH + (col ^ ((row & 7) << 3))] = f2b(sp(acc[mt][nt][r]));
            }
}

// ---- K2: per (i, j-half): 4 chunks of 64 j's; MFMA MLP + online partial LSE ----
__global__ __launch_bounds__(256, 2) void pair_kernel(
    const ushort_t* __restrict__ XWxb, const ushort_t* __restrict__ YWyb,
    const ushort_t* __restrict__ Wt1b, const ushort_t* __restrict__ Wt2b,
    const float* __restrict__ U, const float* __restrict__ Y,
    const float* __restrict__ b1, const float* __restrict__ b2,
    const float* __restrict__ Wout, const float* __restrict__ bout,
    float* __restrict__ psi_arr, float* __restrict__ Mp, float* __restrict__ Sp) {
    __shared__ ushort_t Hs0[64 * HH];   // H0 / H2 (swizzled bf16)
    __shared__ ushort_t Hs1[64 * HH];   // H1
    __shared__ float WoutS[HH];
    __shared__ float slackS[64];

    const int i = blockIdx.x;
    const int half = blockIdx.y;
    const int t = threadIdx.x;
    const int wv = t >> 6;
    const int r16 = t & 15;
    const int g4 = (t >> 4) & 3;
    const int n0w = wv * 32;

    float bias1[2], bias2[2];
    bias1[0] = b1[n0w + r16];      bias1[1] = b1[n0w + 16 + r16];
    bias2[0] = b2[n0w + r16];      bias2[1] = b2[n0w + 16 + r16];
    const float boutv = bout[0];
    if (t < HH) WoutS[t] = Wout[t];

    const int hcol = t & 127;
    const float axh = b2f(XWxb[i * HH + hcol]);   // includes b0

    float Ur[RR];
#pragma unroll
    for (int r = 0; r < RR; ++r) Ur[r] = U[i * RR + r];

    float m_l = -INFINITY, s_l = 0.f;

    for (int c = 0; c < 4; ++c) {
        const int j0 = half * 256 + c * 64;
        // ---- stage H0 = softplus(axh + YWy[j]) bf16, XOR-swizzled ----
#pragma unroll
        for (int s = 0; s < 32; ++s) {
            const int p = (t >> 7) + 2 * s;
            const float v = axh + b2f(YWyb[(j0 + p) * HH + hcol]);
            Hs0[p * HH + (hcol ^ ((p & 7) << 3))] = f2b(sp(v));
        }
        __syncthreads();
        layer_mfma(Hs0, Wt1b, Hs1, bias1, r16, g4, n0w);
        __syncthreads();
        layer_mfma(Hs1, Wt2b, Hs0, bias2, r16, g4, n0w);
        __syncthreads();
        // ---- epilogue: psi = H2 . Wout + bout; slack = U[i].Y[j] - psi ----
        {
            const int p = t >> 2, q = t & 3;
            float acc = 0.f;
#pragma unroll
            for (int uu = 0; uu < 4; ++uu) {
                const int ebase = q * 32 + uu * 8;
                bf16x8 hv = *(const bf16x8*)&Hs0[p * HH + (ebase ^ ((p & 7) << 3))];
#pragma unroll
                for (int e = 0; e < 8; ++e)
                    acc += b2f((ushort_t)hv[e]) * WoutS[ebase + e];
            }
            acc += __shfl_xor(acc, 1);
            acc += __shfl_xor(acc, 2);
            if (q == 0) {
                const float psi = acc + boutv;
                const int j = j0 + p;
                float cost = 0.f;
#pragma unroll
                for (int r = 0; r < RR; ++r) cost += Ur[r] * Y[j * RR + r];
                slackS[p] = cost - psi;
                if (j == i) psi_arr[i] = psi;
            }
        }
        __syncthreads();
        if (t < 64) {
            const float sv = slackS[t];
            const float mn = fmaxf(m_l, sv);
            s_l = s_l * __expf((m_l - mn) * INV_EPS) + __expf((sv - mn) * INV_EPS);
            m_l = mn;
        }
    }
    // ---- combine wave-0 lanes' (m,s); write block partial ----
    if (t < 64) {
        float M = m_l;
#pragma unroll
        for (int o = 1; o < 64; o <<= 1) M = fmaxf(M, __shfl_xor(M, o));
        float S = s_l * __expf((m_l - M) * INV_EPS);
#pragma unroll
        for (int o = 1; o < 64; o <<= 1) S += __shfl_xor(S, o);
        if (t == 0) {
            Mp[i * 2 + half] = M;
            Sp[i * 2 + half] = S;
        }
    }
}

// ---- K3: combine per-half partials -> phi_i; total = mean(phi) + mean(psi) ----
__global__ __launch_bounds__(512) void finalize_kernel(
    const float* __restrict__ psi_arr, const float* __restrict__ Mp,
    const float* __restrict__ Sp, float* __restrict__ out) {
    __shared__ float red[8];
    const int t = threadIdx.x;  // = i
    const float M0 = Mp[2 * t], M1 = Mp[2 * t + 1];
    const float S0 = Sp[2 * t], S1 = Sp[2 * t + 1];
    const float Mg = fmaxf(M0, M1);
    const float S = S0 * __expf((M0 - Mg) * INV_EPS) + S1 * __expf((M1 - Mg) * INV_EPS);
    const float phi = EPSV * (__logf(S) - __logf((float)NN)) + Mg;
    float v = phi + psi_arr[t];
#pragma unroll
    for (int o = 1; o < 64; o <<= 1) v += __shfl_xor(v, o);
    if ((t & 63) == 0) red[t >> 6] = v;
    __syncthreads();
    if (t == 0) {
        float tot = 0.f;
#pragma unroll
        for (int w = 0; w < 8; ++w) tot += red[w];
        out[0] = tot / (float)NN;
    }
}

extern "C" void kernel_launch(void* const* d_in, const int* in_sizes, int n_in,
                              void* d_out, int out_size, void* d_ws, size_t ws_size,
                              hipStream_t stream) {
    (void)in_sizes; (void)n_in; (void)out_size; (void)ws_size;
    const float* X    = (const float*)d_in[0];
    const float* U    = (const float*)d_in[1];
    const float* Y    = (const float*)d_in[2];
    const float* Wx   = (const float*)d_in[3];
    const float* Wy   = (const float*)d_in[4];
    const float* b0   = (const float*)d_in[5];
    const float* W1   = (const float*)d_in[6];
    const float* b1   = (const float*)d_in[7];
    const float* W2   = (const float*)d_in[8];
    const float* b2   = (const float*)d_in[9];
    const float* Wout = (const float*)d_in[10];
    const float* bout = (const float*)d_in[11];
    float* out = (float*)d_out;

    char* ws = (char*)d_ws;
    ushort_t* Wt1b   = (ushort_t*)(ws);                    // 32 KB
    ushort_t* Wt2b   = (ushort_t*)(ws + 32768);            // 32 KB
    ushort_t* XWxb   = (ushort_t*)(ws + 65536);            // 128 KB
    ushort_t* YWyb   = (ushort_t*)(ws + 196608);           // 128 KB
    float*    psi_arr = (float*)(ws + 327680);             // 2 KB
    float*    Mp      = (float*)(ws + 329728);             // 4 KB
    float*    Sp      = (float*)(ws + 333824);             // 4 KB

    prep_w_kernel<<<128, 256, 0, stream>>>(W1, W2, Wt1b, Wt2b);
    prep_xy_kernel<<<512, 256, 0, stream>>>(X, Y, Wx, Wy, b0, XWxb, YWyb);
    pair_kernel<<<dim3(NN, 2), 256, 0, stream>>>(XWxb, YWyb, Wt1b, Wt2b, U, Y,
                                                 b1, b2, Wout, bout, psi_arr, Mp, Sp);
    finalize_kernel<<<1, 512, 0, stream>>>(psi_arr, Mp, Sp, out);
}